// Round 12
// baseline (266.345 us; speedup 1.0000x reference)
//
#include <hip/hip_runtime.h>
#include <math.h>

#define N 4096
#define IN_F 256
#define OUT_F 64
#define HEADS 4
#define NEG 0.2f
#define JSPLIT 8
#define JLEN (N / JSPLIT)        // 512
#define NC (JLEN / 32)           // 16 chunks
#define LOG2E 1.44269504088896f

typedef float f32x4 __attribute__((ext_vector_type(4)));
typedef float f32x2 __attribute__((ext_vector_type(2)));
typedef short short8 __attribute__((ext_vector_type(8)));

#define FMA4S(A, s, V) do { (A).x = fmaf((s),(V).x,(A).x); (A).y = fmaf((s),(V).y,(A).y); \
                            (A).z = fmaf((s),(V).z,(A).z); (A).w = fmaf((s),(V).w,(A).w); } while(0)

// zero P unless bit R of MS is set: AND float bits with sign-extended bit
#define MSEL(P, MS, R) (P) = __uint_as_float(__float_as_uint(P) & \
                         (unsigned)(((int)((MS) << (31 - (R)))) >> 31))

__device__ __forceinline__ unsigned short f2bf(float x) {
  unsigned int u = __float_as_uint(x);
  u += 0x7fffu + ((u >> 16) & 1u);   // RNE
  return (unsigned short)(u >> 16);
}

__device__ __forceinline__ float exp2_fast(float x) {
#if __has_builtin(__builtin_amdgcn_exp2f)
  return __builtin_amdgcn_exp2f(x);
#else
  return exp2f(x);
#endif
}

// pack bf16(p1)<<16 | bf16(p0), round-half-up
__device__ __forceinline__ int pack_bf2(float p0, float p1) {
  unsigned u0 = __float_as_uint(p0) + 0x8000u;
  unsigned u1 = __float_as_uint(p1) + 0x8000u;
  return (int)__builtin_amdgcn_perm(u1, u0, 0x07060302u);
}

// ---------------------------------------------------------------------------
// Kernel 1: fused prep. Blocks [0,512): xt = x @ W[h] (32-row tile, LDS-staged)
// -> src/dst (log2e-scaled) + xtB (bf16 B-frag). Blocks [512,8704): adj ->
// bitmask stream. Block 512 also zeroes the split-K tile counters (ws is
// re-poisoned 0xAA before every launch, so they must be re-zeroed each call).
// ---------------------------------------------------------------------------
__global__ __launch_bounds__(256) void k_prep(const float* __restrict__ x,
                                              const float* __restrict__ W,
                                              const float* __restrict__ a,
                                              const int* __restrict__ adj,
                                              short* __restrict__ xtB,
                                              float* __restrict__ src,
                                              float* __restrict__ dst,
                                              unsigned char* __restrict__ mbB,
                                              int* __restrict__ cnt) {
  __shared__ __align__(16) float xls[32 * 68];
  __shared__ __align__(16) float wls[64 * 64];
  const int t = threadIdx.x;

  if (blockIdx.x >= 512) {
    if (blockIdx.x == 512 && t < 128) cnt[t] = 0;   // split-K counters
    int tid = (blockIdx.x - 512) * 256 + t;
    const int4* a4 = (const int4*)adj + (size_t)tid * 2;
    int4 v0 = a4[0];
    int4 v1 = a4[1];
    unsigned b = 0;
    b |= (v0.x > 0) ? 0x01u : 0u;
    b |= (v0.y > 0) ? 0x02u : 0u;
    b |= (v0.z > 0) ? 0x04u : 0u;
    b |= (v0.w > 0) ? 0x08u : 0u;
    b |= (v1.x > 0) ? 0x10u : 0u;
    b |= (v1.y > 0) ? 0x20u : 0u;
    b |= (v1.z > 0) ? 0x40u : 0u;
    b |= (v1.w > 0) ? 0x80u : 0u;
    mbB[tid] = (unsigned char)b;
    return;
  }

  const int h  = blockIdx.x >> 7;
  const int bx = blockIdx.x & 127;
  const int i0 = bx * 32;
  const int fg = t & 15;
  const int rg = t >> 4;

  float4 acc[2];
  acc[0] = acc[1] = make_float4(0.f, 0.f, 0.f, 0.f);

  const float4* xg = (const float4*)x;
  const float4* wg = (const float4*)W;
  float4* xls4 = (float4*)xls;
  float4* wls4 = (float4*)wls;
  const float4* xr4 = (const float4*)xls;
  const float4* wr4 = (const float4*)wls;

  for (int kt = 0; kt < 4; ++kt) {
    __syncthreads();
    #pragma unroll
    for (int s = 0; s < 2; ++s) {
      int f4i = t + 256 * s;
      int row = f4i >> 4, c4 = f4i & 15;
      xls4[row * 17 + c4] = xg[(size_t)(i0 + row) * 64 + kt * 16 + c4];
    }
    #pragma unroll
    for (int s = 0; s < 4; ++s) {
      int f4i = t + 256 * s;
      int kk = f4i >> 4, c4 = f4i & 15;
      wls4[kk * 16 + c4] = wg[(size_t)(h * 256 + kt * 64 + kk) * 16 + c4];
    }
    __syncthreads();
    #pragma unroll 4
    for (int kk = 0; kk < 64; kk += 4) {
      float4 wv0 = wr4[(kk + 0) * 16 + fg];
      float4 wv1 = wr4[(kk + 1) * 16 + fg];
      float4 wv2 = wr4[(kk + 2) * 16 + fg];
      float4 wv3 = wr4[(kk + 3) * 16 + fg];
      #pragma unroll
      for (int q = 0; q < 2; ++q) {
        float4 xv = xr4[(rg * 2 + q) * 17 + (kk >> 2)];
        FMA4S(acc[q], xv.x, wv0);
        FMA4S(acc[q], xv.y, wv1);
        FMA4S(acc[q], xv.z, wv2);
        FMA4S(acc[q], xv.w, wv3);
      }
    }
  }

  const float4* a4 = (const float4*)a;
  float4 as = a4[h * 32 + fg];
  float4 ad = a4[h * 32 + 16 + fg];
  as.x *= LOG2E; as.y *= LOG2E; as.z *= LOG2E; as.w *= LOG2E;
  ad.x *= LOG2E; ad.y *= LOG2E; ad.z *= LOG2E; ad.w *= LOG2E;
  #pragma unroll
  for (int q = 0; q < 2; ++q) {
    float s_ = acc[q].x * as.x + acc[q].y * as.y + acc[q].z * as.z + acc[q].w * as.w;
    float d_ = acc[q].x * ad.x + acc[q].y * ad.y + acc[q].z * ad.z + acc[q].w * ad.w;
    #pragma unroll
    for (int off = 1; off < 16; off <<= 1) {
      s_ += __shfl_xor(s_, off, 64);
      d_ += __shfl_xor(d_, off, 64);
    }
    if (fg == 0) {
      int r = rg * 2 + q;
      src[h * N + i0 + r] = s_;
      dst[h * N + i0 + r] = d_;
    }
  }

  __syncthreads();
  #pragma unroll
  for (int q = 0; q < 2; ++q) {
    *(float4*)&xls[(rg * 2 + q) * 68 + fg * 4] = acc[q];
  }
  __syncthreads();

  {
    const int lane = t & 63;
    const int g    = t >> 6;
    const int q    = lane >> 4;
    const int m    = lane & 15;
    short8 bv;
    #pragma unroll
    for (int r = 0; r < 8; ++r) {
      bv[r] = (short)f2bf(xls[(q * 8 + r) * 68 + g * 16 + m]);
    }
    ((short8*)xtB)[((size_t)(h * 128 + bx) * 4 + g) * 64 + lane] = bv;
  }
}

// ---------------------------------------------------------------------------
// Kernel 2: fused flash PV + split-K last-tile reduction.
// grid (128, JSPLIT=8), block 256 (wave = head). R6 copy-prefetch; bitmask
// adj; f32x2 packed logit math; bf16-pair partial O. After storing partials:
// device release fence + per-tile atomic counter; the 8th arrival acquires
// and reduces its 32-row tile into `out` (replaces k_div).
// ---------------------------------------------------------------------------
__global__ __launch_bounds__(256) void k_flash(const unsigned* __restrict__ mb,
                                               const float* __restrict__ src,
                                               const float* __restrict__ dst,
                                               const short* __restrict__ xtB,
                                               unsigned* __restrict__ accPu,
                                               float* __restrict__ lP,
                                               int* __restrict__ cnt,
                                               float* __restrict__ out) {
  __shared__ __align__(16) float dls[HEADS][JLEN + 4];
  __shared__ int is_last;
  const int t    = threadIdx.x;
  const int lane = t & 63;
  const int h    = t >> 6;
  const int i0   = blockIdx.x * 32;
  const int js   = blockIdx.y;
  const int q    = lane >> 4;
  const int m    = lane & 15;
  const int koff = q * 8;
  const int jbase = js * JLEN;

  #pragma unroll
  for (int s = 0; s < 2; ++s) {
    int idx = t + 256 * s;
    int hh = idx >> 7, j4 = idx & 127;
    *(float4*)&dls[hh][j4 * 4] = *(const float4*)(dst + (size_t)hh * N + jbase + j4 * 4);
  }

  float sv = (lane < 32) ? src[h * N + i0 + lane] : 0.f;
  const float s0 = __shfl(sv, m, 64);
  const float s1 = __shfl(sv, 16 + m, 64);
  __syncthreads();

  f32x4 acc0[4], acc1[4], accL0, accL1;
  #pragma unroll
  for (int g = 0; g < 4; ++g) { acc0[g] = (f32x4)(0.f); acc1[g] = (f32x4)(0.f); }
  accL0 = (f32x4)(0.f);
  accL1 = (f32x4)(0.f);

  short8 ones;
  #pragma unroll
  for (int r = 0; r < 8; ++r) ones[r] = (short)0x3F80;

  const f32x2 s02 = (f32x2)(s0);
  const f32x2 s12 = (f32x2)(s1);

  const unsigned* mrow0 = mb + (size_t)(i0 + m) * 128 + (jbase >> 5);
  const unsigned* mrow1 = mb + (size_t)(i0 + 16 + m) * 128 + (jbase >> 5);
  const short8* xbb = (const short8*)xtB + ((size_t)(h * 128 + js * NC) * 4) * 64 + lane;

#define LOADC(DM0, DM1, DB, CIDX) do {                                     \
    DM0 = mrow0[CIDX];                                                     \
    DM1 = mrow1[CIDX];                                                     \
    const short8* bb_ = xbb + (size_t)(CIDX) * 256;                        \
    DB[0] = bb_[0]; DB[1] = bb_[64]; DB[2] = bb_[128]; DB[3] = bb_[192];   \
  } while (0)

#define COMPUTE(CM0, CM1, CB, C) do {                                      \
    const float* dp_ = &dls[h][(C) * 32 + koff];                           \
    union { float4 v[2]; f32x2 h2[4]; float f[8]; } du;                    \
    du.v[0] = *(const float4*)dp_;                                         \
    du.v[1] = *(const float4*)(dp_ + 4);                                   \
    unsigned ms0 = (CM0) >> koff;                                          \
    unsigned ms1 = (CM1) >> koff;                                          \
    int av0[4], av1[4];                                                    \
    _Pragma("unroll")                                                      \
    for (int r2 = 0; r2 < 4; ++r2) {                                       \
      f32x2 d2 = du.h2[r2];                                                \
      f32x2 e0 = s02 + d2;                                                 \
      f32x2 el0 = __builtin_elementwise_max(e0, e0 * NEG);                 \
      f32x2 e1 = s12 + d2;                                                 \
      f32x2 el1 = __builtin_elementwise_max(e1, e1 * NEG);                 \
      float p0a = exp2_fast(el0.x), p0b = exp2_fast(el0.y);                \
      float p1a = exp2_fast(el1.x), p1b = exp2_fast(el1.y);                \
      MSEL(p0a, ms0, 2 * r2);  MSEL(p0b, ms0, 2 * r2 + 1);                 \
      MSEL(p1a, ms1, 2 * r2);  MSEL(p1b, ms1, 2 * r2 + 1);                 \
      av0[r2] = pack_bf2(p0a, p0b);                                        \
      av1[r2] = pack_bf2(p1a, p1b);                                        \
    }                                                                      \
    short8 af0 = __builtin_bit_cast(short8, *(int4*)av0);                  \
    short8 af1 = __builtin_bit_cast(short8, *(int4*)av1);                  \
    acc0[0] = __builtin_amdgcn_mfma_f32_16x16x32_bf16(af0, CB[0], acc0[0], 0, 0, 0); \
    acc0[1] = __builtin_amdgcn_mfma_f32_16x16x32_bf16(af0, CB[1], acc0[1], 0, 0, 0); \
    acc0[2] = __builtin_amdgcn_mfma_f32_16x16x32_bf16(af0, CB[2], acc0[2], 0, 0, 0); \
    acc0[3] = __builtin_amdgcn_mfma_f32_16x16x32_bf16(af0, CB[3], acc0[3], 0, 0, 0); \
    accL0   = __builtin_amdgcn_mfma_f32_16x16x32_bf16(af0, ones,  accL0,   0, 0, 0); \
    acc1[0] = __builtin_amdgcn_mfma_f32_16x16x32_bf16(af1, CB[0], acc1[0], 0, 0, 0); \
    acc1[1] = __builtin_amdgcn_mfma_f32_16x16x32_bf16(af1, CB[1], acc1[1], 0, 0, 0); \
    acc1[2] = __builtin_amdgcn_mfma_f32_16x16x32_bf16(af1, CB[2], acc1[2], 0, 0, 0); \
    acc1[3] = __builtin_amdgcn_mfma_f32_16x16x32_bf16(af1, CB[3], acc1[3], 0, 0, 0); \
    accL1   = __builtin_amdgcn_mfma_f32_16x16x32_bf16(af1, ones,  accL1,   0, 0, 0); \
  } while (0)

  unsigned cM0, cM1, nM0, nM1;
  short8 cB[4], nB[4];
  LOADC(cM0, cM1, cB, 0);

  for (int c = 0; c < NC; ++c) {
    const int cn = (c + 1 < NC) ? c + 1 : c;
    LOADC(nM0, nM1, nB, cn);

    COMPUTE(cM0, cM1, cB, c);

    cM0 = nM0; cM1 = nM1;
    #pragma unroll
    for (int z = 0; z < 4; ++z) cB[z] = nB[z];
  }
#undef LOADC
#undef COMPUTE

  float* lp = lP + (size_t)js * (HEADS * N);
  if (m == 0) {
    #pragma unroll
    for (int reg = 0; reg < 4; ++reg) {
      lp[h * N + i0 + q * 4 + reg] = accL0[reg];
      lp[h * N + i0 + 16 + q * 4 + reg] = accL1[reg];
    }
  }

  // bf16-packed partial O: (g0,g1) -> row*32+m, (g2,g3) -> row*32+16+m
  unsigned* ap = accPu + (size_t)js * ((size_t)HEADS * N * 32);
  #pragma unroll
  for (int reg = 0; reg < 4; ++reg) {
    int row0 = i0 + q * 4 + reg;
    int row1 = row0 + 16;
    ap[((size_t)h * N + row0) * 32 + m]      = (unsigned)pack_bf2(acc0[0][reg], acc0[1][reg]);
    ap[((size_t)h * N + row0) * 32 + 16 + m] = (unsigned)pack_bf2(acc0[2][reg], acc0[3][reg]);
    ap[((size_t)h * N + row1) * 32 + m]      = (unsigned)pack_bf2(acc1[0][reg], acc1[1][reg]);
    ap[((size_t)h * N + row1) * 32 + 16 + m] = (unsigned)pack_bf2(acc1[2][reg], acc1[3][reg]);
  }

  // ---- split-K last-tile reduction (replaces k_div) ----
  __threadfence();                                   // release partials device-wide
  if (t == 0) is_last = (atomicAdd(&cnt[blockIdx.x], 1) == JSPLIT - 1);
  __syncthreads();
  if (!is_last) return;
  __threadfence();                                   // acquire others' partials

  #pragma unroll
  for (int w8 = 0; w8 < 8; ++w8) {
    int w = t + w8 * 256;                            // 0..2047 float4 of this tile
    int col4 = w & 63;
    int i    = i0 + (w >> 6);
    int hh   = col4 >> 4;
    int fl   = (col4 & 15) * 4;
    int g    = fl >> 4;
    int m0   = fl & 15;
    size_t base = ((size_t)hh * N + i) * 32 + (size_t)((g >> 1) * 16 + m0);
    const int hi = g & 1;
    float4 s = make_float4(0.f, 0.f, 0.f, 0.f);
    float ls = 0.f;
    #pragma unroll
    for (int j2 = 0; j2 < JSPLIT; ++j2) {
      const uint4 u = *(const uint4*)(accPu + (size_t)j2 * ((size_t)HEADS * N * 32) + base);
      s.x += __uint_as_float(hi ? (u.x & 0xffff0000u) : (u.x << 16));
      s.y += __uint_as_float(hi ? (u.y & 0xffff0000u) : (u.y << 16));
      s.z += __uint_as_float(hi ? (u.z & 0xffff0000u) : (u.z << 16));
      s.w += __uint_as_float(hi ? (u.w & 0xffff0000u) : (u.w << 16));
      ls += lP[(size_t)j2 * (HEADS * N) + hh * N + i];
    }
    float il = 1.f / ls;
    ((float4*)out)[(size_t)i * 64 + col4] = make_float4(s.x * il, s.y * il, s.z * il, s.w * il);
  }
}

extern "C" void kernel_launch(void* const* d_in, const int* in_sizes, int n_in,
                              void* d_out, int out_size, void* d_ws, size_t ws_size,
                              hipStream_t stream) {
  const float* x   = (const float*)d_in[0];
  const float* W   = (const float*)d_in[1];
  const float* a   = (const float*)d_in[2];
  const int*   adj = (const int*)d_in[3];
  float* out = (float*)d_out;

  float* ws    = (float*)d_ws;
  short* xtB   = (short*)ws;                                // 2 MB
  float* src   = ws + 524288;                               // H*N
  float* dst   = src + HEADS * N;                           // H*N
  unsigned* accPu = (unsigned*)(dst + HEADS * N);           // JSPLIT*H*N*32 u32 = 16.8 MB
  float* lP    = (float*)(accPu + (size_t)JSPLIT * HEADS * N * 32);  // JSPLIT*H*N
  unsigned* mb = (unsigned*)(lP + JSPLIT * HEADS * N);      // N*128 u32 = 2 MB
  int* cnt     = (int*)(mb + N * 128);                      // 128 tile counters

  k_prep<<<dim3(512 + N * N / 8 / 256), 256, 0, stream>>>(x, W, a, adj, xtB, src, dst,
                                                          (unsigned char*)mb, cnt);
  k_flash<<<dim3(N / 32, JSPLIT), 256, 0, stream>>>(mb, src, dst, xtB, accPu, lP, cnt, out);
}

// Round 13
// 139.456 us; speedup vs baseline: 1.9099x; 1.9099x over previous
//
#include <hip/hip_runtime.h>
#include <math.h>

#define N 4096
#define IN_F 256
#define OUT_F 64
#define HEADS 4
#define NEG 0.2f
#define JSPLIT 8
#define JLEN (N / JSPLIT)        // 512
#define NC (JLEN / 32)           // 16 chunks
#define LOG2E 1.44269504088896f

typedef float f32x4 __attribute__((ext_vector_type(4)));
typedef float f32x2 __attribute__((ext_vector_type(2)));
typedef short short8 __attribute__((ext_vector_type(8)));

#define FMA4S(A, s, V) do { (A).x = fmaf((s),(V).x,(A).x); (A).y = fmaf((s),(V).y,(A).y); \
                            (A).z = fmaf((s),(V).z,(A).z); (A).w = fmaf((s),(V).w,(A).w); } while(0)

// zero P unless bit R of MS is set: AND float bits with sign-extended bit
#define MSEL(P, MS, R) (P) = __uint_as_float(__float_as_uint(P) & \
                         (unsigned)(((int)((MS) << (31 - (R)))) >> 31))

__device__ __forceinline__ unsigned short f2bf(float x) {
  unsigned int u = __float_as_uint(x);
  u += 0x7fffu + ((u >> 16) & 1u);   // RNE
  return (unsigned short)(u >> 16);
}

__device__ __forceinline__ float exp2_fast(float x) {
#if __has_builtin(__builtin_amdgcn_exp2f)
  return __builtin_amdgcn_exp2f(x);
#else
  return exp2f(x);
#endif
}

// pack bf16(p1)<<16 | bf16(p0), round-half-up
__device__ __forceinline__ int pack_bf2(float p0, float p1) {
  unsigned u0 = __float_as_uint(p0) + 0x8000u;
  unsigned u1 = __float_as_uint(p1) + 0x8000u;
  return (int)__builtin_amdgcn_perm(u1, u0, 0x07060302u);
}

// ---------------------------------------------------------------------------
// Kernel 1: fused prep. Blocks [0,512): xt = x @ W[h] (32-row tile, LDS-staged)
// -> src/dst (log2e-scaled) + xtB (bf16 B-frag). Blocks [512,8704): adj ->
// bitmask stream. Data-independent partitions overlap HBM stream with GEMM.
// NOTE (R12 lesson): do NOT fuse the reduction into k_flash with device
// fences — agent-scope __threadfence() per block causes a cross-XCD L2
// writeback/invalidate storm (172 µs vs 28 µs). Kernel boundary is cheaper.
// ---------------------------------------------------------------------------
__global__ __launch_bounds__(256) void k_prep(const float* __restrict__ x,
                                              const float* __restrict__ W,
                                              const float* __restrict__ a,
                                              const int* __restrict__ adj,
                                              short* __restrict__ xtB,
                                              float* __restrict__ src,
                                              float* __restrict__ dst,
                                              unsigned char* __restrict__ mbB) {
  __shared__ __align__(16) float xls[32 * 68];
  __shared__ __align__(16) float wls[64 * 64];
  const int t = threadIdx.x;

  if (blockIdx.x >= 512) {
    int tid = (blockIdx.x - 512) * 256 + t;
    const int4* a4 = (const int4*)adj + (size_t)tid * 2;
    int4 v0 = a4[0];
    int4 v1 = a4[1];
    unsigned b = 0;
    b |= (v0.x > 0) ? 0x01u : 0u;
    b |= (v0.y > 0) ? 0x02u : 0u;
    b |= (v0.z > 0) ? 0x04u : 0u;
    b |= (v0.w > 0) ? 0x08u : 0u;
    b |= (v1.x > 0) ? 0x10u : 0u;
    b |= (v1.y > 0) ? 0x20u : 0u;
    b |= (v1.z > 0) ? 0x40u : 0u;
    b |= (v1.w > 0) ? 0x80u : 0u;
    mbB[tid] = (unsigned char)b;
    return;
  }

  const int h  = blockIdx.x >> 7;
  const int bx = blockIdx.x & 127;
  const int i0 = bx * 32;
  const int fg = t & 15;
  const int rg = t >> 4;

  float4 acc[2];
  acc[0] = acc[1] = make_float4(0.f, 0.f, 0.f, 0.f);

  const float4* xg = (const float4*)x;
  const float4* wg = (const float4*)W;
  float4* xls4 = (float4*)xls;
  float4* wls4 = (float4*)wls;
  const float4* xr4 = (const float4*)xls;
  const float4* wr4 = (const float4*)wls;

  for (int kt = 0; kt < 4; ++kt) {
    __syncthreads();
    #pragma unroll
    for (int s = 0; s < 2; ++s) {
      int f4i = t + 256 * s;
      int row = f4i >> 4, c4 = f4i & 15;
      xls4[row * 17 + c4] = xg[(size_t)(i0 + row) * 64 + kt * 16 + c4];
    }
    #pragma unroll
    for (int s = 0; s < 4; ++s) {
      int f4i = t + 256 * s;
      int kk = f4i >> 4, c4 = f4i & 15;
      wls4[kk * 16 + c4] = wg[(size_t)(h * 256 + kt * 64 + kk) * 16 + c4];
    }
    __syncthreads();
    #pragma unroll 4
    for (int kk = 0; kk < 64; kk += 4) {
      float4 wv0 = wr4[(kk + 0) * 16 + fg];
      float4 wv1 = wr4[(kk + 1) * 16 + fg];
      float4 wv2 = wr4[(kk + 2) * 16 + fg];
      float4 wv3 = wr4[(kk + 3) * 16 + fg];
      #pragma unroll
      for (int q = 0; q < 2; ++q) {
        float4 xv = xr4[(rg * 2 + q) * 17 + (kk >> 2)];
        FMA4S(acc[q], xv.x, wv0);
        FMA4S(acc[q], xv.y, wv1);
        FMA4S(acc[q], xv.z, wv2);
        FMA4S(acc[q], xv.w, wv3);
      }
    }
  }

  const float4* a4 = (const float4*)a;
  float4 as = a4[h * 32 + fg];
  float4 ad = a4[h * 32 + 16 + fg];
  as.x *= LOG2E; as.y *= LOG2E; as.z *= LOG2E; as.w *= LOG2E;
  ad.x *= LOG2E; ad.y *= LOG2E; ad.z *= LOG2E; ad.w *= LOG2E;
  #pragma unroll
  for (int q = 0; q < 2; ++q) {
    float s_ = acc[q].x * as.x + acc[q].y * as.y + acc[q].z * as.z + acc[q].w * as.w;
    float d_ = acc[q].x * ad.x + acc[q].y * ad.y + acc[q].z * ad.z + acc[q].w * ad.w;
    #pragma unroll
    for (int off = 1; off < 16; off <<= 1) {
      s_ += __shfl_xor(s_, off, 64);
      d_ += __shfl_xor(d_, off, 64);
    }
    if (fg == 0) {
      int r = rg * 2 + q;
      src[h * N + i0 + r] = s_;
      dst[h * N + i0 + r] = d_;
    }
  }

  __syncthreads();
  #pragma unroll
  for (int q = 0; q < 2; ++q) {
    *(float4*)&xls[(rg * 2 + q) * 68 + fg * 4] = acc[q];
  }
  __syncthreads();

  {
    const int lane = t & 63;
    const int g    = t >> 6;
    const int q    = lane >> 4;
    const int m    = lane & 15;
    short8 bv;
    #pragma unroll
    for (int r = 0; r < 8; ++r) {
      bv[r] = (short)f2bf(xls[(q * 8 + r) * 68 + g * 16 + m]);
    }
    ((short8*)xtB)[((size_t)(h * 128 + bx) * 4 + g) * 64 + lane] = bv;
  }
}

// ---------------------------------------------------------------------------
// Kernel 2: fused flash PV. grid (128, JSPLIT=8), block 256 (wave = head).
// R6 copy-prefetch structure; bitmask adj; f32x2 packed logit math. Partial O
// stored as bf16 pairs (uint): lane m writes (g0,g1)->row*32+m, (g2,g3)->
// row*32+16+m. fp32 accumulate, one rounding per partial. No atomics/fences.
// ---------------------------------------------------------------------------
__global__ __launch_bounds__(256) void k_flash(const unsigned* __restrict__ mb,
                                               const float* __restrict__ src,
                                               const float* __restrict__ dst,
                                               const short* __restrict__ xtB,
                                               unsigned* __restrict__ accPu,
                                               float* __restrict__ lP) {
  __shared__ __align__(16) float dls[HEADS][JLEN + 4];
  const int t    = threadIdx.x;
  const int lane = t & 63;
  const int h    = t >> 6;
  const int i0   = blockIdx.x * 32;
  const int js   = blockIdx.y;
  const int q    = lane >> 4;
  const int m    = lane & 15;
  const int koff = q * 8;
  const int jbase = js * JLEN;

  #pragma unroll
  for (int s = 0; s < 2; ++s) {
    int idx = t + 256 * s;
    int hh = idx >> 7, j4 = idx & 127;
    *(float4*)&dls[hh][j4 * 4] = *(const float4*)(dst + (size_t)hh * N + jbase + j4 * 4);
  }

  float sv = (lane < 32) ? src[h * N + i0 + lane] : 0.f;
  const float s0 = __shfl(sv, m, 64);
  const float s1 = __shfl(sv, 16 + m, 64);
  __syncthreads();

  f32x4 acc0[4], acc1[4], accL0, accL1;
  #pragma unroll
  for (int g = 0; g < 4; ++g) { acc0[g] = (f32x4)(0.f); acc1[g] = (f32x4)(0.f); }
  accL0 = (f32x4)(0.f);
  accL1 = (f32x4)(0.f);

  short8 ones;
  #pragma unroll
  for (int r = 0; r < 8; ++r) ones[r] = (short)0x3F80;

  const f32x2 s02 = (f32x2)(s0);
  const f32x2 s12 = (f32x2)(s1);

  const unsigned* mrow0 = mb + (size_t)(i0 + m) * 128 + (jbase >> 5);
  const unsigned* mrow1 = mb + (size_t)(i0 + 16 + m) * 128 + (jbase >> 5);
  const short8* xbb = (const short8*)xtB + ((size_t)(h * 128 + js * NC) * 4) * 64 + lane;

#define LOADC(DM0, DM1, DB, CIDX) do {                                     \
    DM0 = mrow0[CIDX];                                                     \
    DM1 = mrow1[CIDX];                                                     \
    const short8* bb_ = xbb + (size_t)(CIDX) * 256;                        \
    DB[0] = bb_[0]; DB[1] = bb_[64]; DB[2] = bb_[128]; DB[3] = bb_[192];   \
  } while (0)

#define COMPUTE(CM0, CM1, CB, C) do {                                      \
    const float* dp_ = &dls[h][(C) * 32 + koff];                           \
    union { float4 v[2]; f32x2 h2[4]; float f[8]; } du;                    \
    du.v[0] = *(const float4*)dp_;                                         \
    du.v[1] = *(const float4*)(dp_ + 4);                                   \
    unsigned ms0 = (CM0) >> koff;                                          \
    unsigned ms1 = (CM1) >> koff;                                          \
    int av0[4], av1[4];                                                    \
    _Pragma("unroll")                                                      \
    for (int r2 = 0; r2 < 4; ++r2) {                                       \
      f32x2 d2 = du.h2[r2];                                                \
      f32x2 e0 = s02 + d2;                                                 \
      f32x2 el0 = __builtin_elementwise_max(e0, e0 * NEG);                 \
      f32x2 e1 = s12 + d2;                                                 \
      f32x2 el1 = __builtin_elementwise_max(e1, e1 * NEG);                 \
      float p0a = exp2_fast(el0.x), p0b = exp2_fast(el0.y);                \
      float p1a = exp2_fast(el1.x), p1b = exp2_fast(el1.y);                \
      MSEL(p0a, ms0, 2 * r2);  MSEL(p0b, ms0, 2 * r2 + 1);                 \
      MSEL(p1a, ms1, 2 * r2);  MSEL(p1b, ms1, 2 * r2 + 1);                 \
      av0[r2] = pack_bf2(p0a, p0b);                                        \
      av1[r2] = pack_bf2(p1a, p1b);                                        \
    }                                                                      \
    short8 af0 = __builtin_bit_cast(short8, *(int4*)av0);                  \
    short8 af1 = __builtin_bit_cast(short8, *(int4*)av1);                  \
    acc0[0] = __builtin_amdgcn_mfma_f32_16x16x32_bf16(af0, CB[0], acc0[0], 0, 0, 0); \
    acc0[1] = __builtin_amdgcn_mfma_f32_16x16x32_bf16(af0, CB[1], acc0[1], 0, 0, 0); \
    acc0[2] = __builtin_amdgcn_mfma_f32_16x16x32_bf16(af0, CB[2], acc0[2], 0, 0, 0); \
    acc0[3] = __builtin_amdgcn_mfma_f32_16x16x32_bf16(af0, CB[3], acc0[3], 0, 0, 0); \
    accL0   = __builtin_amdgcn_mfma_f32_16x16x32_bf16(af0, ones,  accL0,   0, 0, 0); \
    acc1[0] = __builtin_amdgcn_mfma_f32_16x16x32_bf16(af1, CB[0], acc1[0], 0, 0, 0); \
    acc1[1] = __builtin_amdgcn_mfma_f32_16x16x32_bf16(af1, CB[1], acc1[1], 0, 0, 0); \
    acc1[2] = __builtin_amdgcn_mfma_f32_16x16x32_bf16(af1, CB[2], acc1[2], 0, 0, 0); \
    acc1[3] = __builtin_amdgcn_mfma_f32_16x16x32_bf16(af1, CB[3], acc1[3], 0, 0, 0); \
    accL1   = __builtin_amdgcn_mfma_f32_16x16x32_bf16(af1, ones,  accL1,   0, 0, 0); \
  } while (0)

  unsigned cM0, cM1, nM0, nM1;
  short8 cB[4], nB[4];
  LOADC(cM0, cM1, cB, 0);

  for (int c = 0; c < NC; ++c) {
    const int cn = (c + 1 < NC) ? c + 1 : c;
    LOADC(nM0, nM1, nB, cn);

    COMPUTE(cM0, cM1, cB, c);

    cM0 = nM0; cM1 = nM1;
    #pragma unroll
    for (int z = 0; z < 4; ++z) cB[z] = nB[z];
  }
#undef LOADC
#undef COMPUTE

  float* lp = lP + (size_t)js * (HEADS * N);
  if (m == 0) {
    #pragma unroll
    for (int reg = 0; reg < 4; ++reg) {
      lp[h * N + i0 + q * 4 + reg] = accL0[reg];
      lp[h * N + i0 + 16 + q * 4 + reg] = accL1[reg];
    }
  }

  // bf16-packed partial O: (g0,g1) -> row*32+m, (g2,g3) -> row*32+16+m
  unsigned* ap = accPu + (size_t)js * ((size_t)HEADS * N * 32);
  #pragma unroll
  for (int reg = 0; reg < 4; ++reg) {
    int row0 = i0 + q * 4 + reg;
    int row1 = row0 + 16;
    ap[((size_t)h * N + row0) * 32 + m]      = (unsigned)pack_bf2(acc0[0][reg], acc0[1][reg]);
    ap[((size_t)h * N + row0) * 32 + 16 + m] = (unsigned)pack_bf2(acc0[2][reg], acc0[3][reg]);
    ap[((size_t)h * N + row1) * 32 + m]      = (unsigned)pack_bf2(acc1[0][reg], acc1[1][reg]);
    ap[((size_t)h * N + row1) * 32 + 16 + m] = (unsigned)pack_bf2(acc1[2][reg], acc1[3][reg]);
  }
}

// ---------------------------------------------------------------------------
// Kernel 3: out[i][h*64+f] = sum_js unpack(accPu) / sum_js lP
// ---------------------------------------------------------------------------
__global__ __launch_bounds__(256) void k_div(const unsigned* __restrict__ accPu,
                                             const float* __restrict__ lP,
                                             float* __restrict__ out) {
  int v = blockIdx.x * 256 + threadIdx.x;   // float4 index over N*256 floats
  int col4 = v & 63;
  int i    = v >> 6;
  int h    = col4 >> 4;
  int fl   = (col4 & 15) * 4;     // f within head: 0,4,...,60
  int g    = fl >> 4;
  int m0   = fl & 15;
  size_t base = ((size_t)h * N + i) * 32 + (size_t)((g >> 1) * 16 + m0);
  const int hi = g & 1;
  float4 s = make_float4(0.f, 0.f, 0.f, 0.f);
  float ls = 0.f;
  #pragma unroll
  for (int js = 0; js < JSPLIT; ++js) {
    const uint4 u = *(const uint4*)(accPu + (size_t)js * ((size_t)HEADS * N * 32) + base);
    s.x += __uint_as_float(hi ? (u.x & 0xffff0000u) : (u.x << 16));
    s.y += __uint_as_float(hi ? (u.y & 0xffff0000u) : (u.y << 16));
    s.z += __uint_as_float(hi ? (u.z & 0xffff0000u) : (u.z << 16));
    s.w += __uint_as_float(hi ? (u.w & 0xffff0000u) : (u.w << 16));
    ls += lP[(size_t)js * (HEADS * N) + h * N + i];
  }
  float il = 1.f / ls;
  ((float4*)out)[v] = make_float4(s.x * il, s.y * il, s.z * il, s.w * il);
}

extern "C" void kernel_launch(void* const* d_in, const int* in_sizes, int n_in,
                              void* d_out, int out_size, void* d_ws, size_t ws_size,
                              hipStream_t stream) {
  const float* x   = (const float*)d_in[0];
  const float* W   = (const float*)d_in[1];
  const float* a   = (const float*)d_in[2];
  const int*   adj = (const int*)d_in[3];
  float* out = (float*)d_out;

  float* ws    = (float*)d_ws;
  short* xtB   = (short*)ws;                                // 2 MB
  float* src   = ws + 524288;                               // H*N
  float* dst   = src + HEADS * N;                           // H*N
  unsigned* accPu = (unsigned*)(dst + HEADS * N);           // JSPLIT*H*N*32 u32 = 16.8 MB
  float* lP    = (float*)(accPu + (size_t)JSPLIT * HEADS * N * 32);  // JSPLIT*H*N
  unsigned* mb = (unsigned*)(lP + JSPLIT * HEADS * N);      // N*128 u32 = 2 MB

  k_prep<<<dim3(512 + N * N / 8 / 256), 256, 0, stream>>>(x, W, a, adj, xtB, src, dst,
                                                          (unsigned char*)mb);
  k_flash<<<dim3(N / 32, JSPLIT), 256, 0, stream>>>(mb, src, dst, xtB, accPu, lP);
  k_div<<<dim3((N * OUT_F) / 256), 256, 0, stream>>>(accPu, lP, out);
}